// Round 8
// baseline (458.919 us; speedup 1.0000x reference)
//
#include <hip/hip_runtime.h>
#include <string.h>

// TopographicIntentMap R8: kill the weight cvt + trim gather padding.
// R7 was VALU-issue-bound (~30cy/entry); half of that was 2x v_cvt_f64_f32
// per entry on the half-rate f64 pipe. The weight convert is tick-invariant:
// prep now stores (double)w in a SoA stream {colByte u32[], wgt f64[]}
// (~26KB/block/tick -> L1-resident). Rows pad to x2 (was x4): nnz 2506->2146,
// DS floor 436K->373K cyc. Arithmetic BIT-IDENTICAL to R5-R7: same k-ascending
// exact-f64 sums, (double)w precomputed == runtime cvt, zero pads exact no-ops.
//  - 2-entry chunks, unrolled x2, zero-mov steady state, depth-2 prefetch.
//  - acc in LDS as f32 (exact ints <= 30), double-buffered, 1 barrier/tick.
//  - per-entry VALU: v_add(addr) + cvt(acc) + fma_f64  ~10cy < DS 5.8cy*SIMD share.

#define NN 144
#define NE 115
#define NB 64            // batches per block (= lanes)
#define RPW 9            // rows per wave: 16*9 = 144
#define THREADS 1024

// ws layout (bytes):
//   [0 .. 580)        int rowptr[145] (padded-to-2 row sizes)
//   [4096 .. +~12KB)  u32 colByte[] = col*256
//   [20480 .. +~24KB) f64 wgt[]
#define COL_OFF_B 4096
#define WGT_OFF_B 20480

__global__ void prep_kernel(const float* __restrict__ W_rec,
                            int* __restrict__ wsI, char* __restrict__ wsB) {
    __shared__ int cnt[NN];
    __shared__ int rp[NN + 1];
    int t = threadIdx.x;

    if (t < NN) {
        int c = 0;
        for (int j = 0; j < NN; ++j) c += (W_rec[t * NN + j] != 0.0f);
        cnt[t] = c;
    }
    __syncthreads();
    if (t == 0) {
        int s = 0; rp[0] = 0;
        for (int o = 0; o < NN; ++o) { s += (cnt[o] + 1) & ~1; rp[o + 1] = s; }
    }
    __syncthreads();
    if (t <= NN) wsI[t] = rp[t];
    unsigned* colB = (unsigned*)(wsB + COL_OFF_B);
    double*   wgt  = (double*)(wsB + WGT_OFF_B);
    if (t < NN) {
        int p = rp[t];
        for (int j = 0; j < NN; ++j) {
            float w = W_rec[t * NN + j];
            if (w != 0.0f) {
                colB[p] = (unsigned)j * 256u;
                wgt[p]  = (double)w;          // same value as runtime cvt
                ++p;
            }
        }
        for (; p < rp[t + 1]; ++p) { colB[p] = 0u; wgt[p] = 0.0; }  // exact pads
    }
    if (t < 16) {                              // pipeline-overrun tail
        int p = rp[NN] + t;
        colB[p] = 0u; wgt[p] = 0.0;
    }
}

// 2 entries: cols in uint2 C, weights in double2 W; k-ascending f64 FMAs.
#define GFMA2(C, W)                                                     \
    {                                                                   \
        float a0 = *(const float*)(RbB + ((C).x + laneB));              \
        float a1 = *(const float*)(RbB + ((C).y + laneB));              \
        rec += (W).x * (double)a0;                                      \
        rec += (W).y * (double)a1;                                      \
    }

__global__ __launch_bounds__(THREADS) void snn_kernel(
        const int*   __restrict__ actions,
        const float* __restrict__ spk,      // [B,8,115]
        const float* __restrict__ W_inh,    // [144,115]
        const int*   __restrict__ wsI,      // padded rowptr
        const char*  __restrict__ wsB,      // SoA csr base
        const int*   __restrict__ nt_ptr,
        float*       __restrict__ out,      // [B,115]
        int B) {
    __shared__ float accF[2][NN * NB];      // 73728 B, double-buffered
    __shared__ int   rpL[NN + 1];

    float* nbF = (float*)&accF[1][0];       // [NE][65] alias, pre-loop only

    const int t    = threadIdx.x;
    const int lane = t & 63;
    const int wid  = t >> 6;
    const int b0   = blockIdx.x * NB;
    const int b    = b0 + lane;
    const int ticks = *nt_ptr;
    const int R0   = wid * RPW;
    const unsigned laneB = (unsigned)lane * 4u;

    // opaque per-lane zero: keeps CSR streams on the vector VMEM path (vmcnt)
    int vz;
    asm volatile("v_mov_b32 %0, 0" : "=v"(vz));

    if (t <= NN) rpL[t] = wsI[t];

    // stage neighbor sums into nbF[e][bb]
    for (int p = t; p < NB * NE; p += THREADS) {
        int bb = p / NE;
        int e  = p - bb * NE;
        float s = 0.0f;
        if (b0 + bb < B) {
            const float* sp = spk + ((size_t)(b0 + bb) * 8) * NE + e;
            #pragma unroll
            for (int n = 0; n < 8; ++n) s += sp[n * NE];
        }
        nbF[e * (NB + 1) + bb] = s;
    }
    for (int i = t; i < NN * NB; i += THREADS) accF[0][i] = 0.0f;
    __syncthreads();

    // per-row drives (fp64, e ascending — unchanged association)
    const int R0s = __builtin_amdgcn_readfirstlane(R0);
    double drv[RPW];
    {
        int a = (b < B) ? actions[b] : 4;
        int cell = (a == 0) ? 5 : (a == 1) ? 1 : (a == 2) ? 3 : (a == 3) ? 7 : 4;
        int cs = cell * 16;
        #pragma unroll
        for (int r = 0; r < RPW; ++r) {
            double inh = 0.0;
            for (int e = 0; e < NE; ++e)
                inh += (double)nbF[e * (NB + 1) + lane]
                     * (double)W_inh[(R0s + r) * NE + e];
            int o = R0 + r;
            double ic = (o >= cs && o < cs + 16) ? 5.0 : 0.0;
            drv[r] = 0.5 * ic - 0.5 * inh;
        }
    }

    int sk0[RPW], sk1[RPW];
    #pragma unroll
    for (int r = 0; r < RPW; ++r) {
        sk0[r] = __builtin_amdgcn_readfirstlane(rpL[R0 + r]);
        sk1[r] = __builtin_amdgcn_readfirstlane(rpL[R0 + r + 1]);
    }
    // chunk = 2 entries; per-lane stream base pointers (vz -> VMEM path)
    const int q00 = sk0[0] >> 1;
    const uint2*   pC0 = (const uint2*)(wsB + COL_OFF_B) + q00 + vz;
    const double2* pW0 = (const double2*)(wsB + WGT_OFF_B) + q00 + vz;

    double v[RPW];
    float  accv[RPW];
    #pragma unroll
    for (int r = 0; r < RPW; ++r) { v[r] = 0.0; accv[r] = 0.0f; }

    for (int tk = 0; tk < ticks; ++tk) {
        __syncthreads();   // prev tick's acc writes (or initial zeros) visible
        const float* __restrict__ Rb = accF[tk & 1];
        float*       __restrict__ Wb = accF[(tk & 1) ^ 1];
        const char*  RbB = (const char*)Rb;

        // prime: SA = entries k..k+1, SB = k+2..k+3 (flat stream)
        const uint2*   pC = pC0;
        const double2* pW = pW0;
        uint2   SAc = pC[0]; double2 SAw = pW[0];
        uint2   SBc = pC[1]; double2 SBw = pW[1];

        #pragma unroll
        for (int r = 0; r < RPW; ++r) {
            const int o = R0 + r;
            double rec = 0.0;
            int k = sk0[r];
            const int kend = sk1[r];
            // steady state: 2 chunks (4 entries)/iter, zero rotation movs
            while (k + 4 <= kend) {
                GFMA2(SAc, SAw);
                SAc = pC[2]; SAw = pW[2];        // entries k+4..k+5
                GFMA2(SBc, SBw);
                SBc = pC[3]; SBw = pW[3];        // entries k+6..k+7
                pC += 2; pW += 2; k += 4;
            }
            if (k < kend) {                      // one leftover chunk in SA
                GFMA2(SAc, SAw);
                SAc = SBc; SAw = SBw;            // once-per-odd-row movs
                SBc = pC[2]; SBw = pW[2];
                pC += 1; pW += 1;
            }
            // invariant: SA = next row's first chunk, SB = second
            double x = drv[r] + 0.3 * ((o < NE) ? rec : -rec);
            double vv = v[r];
            vv += (x - vv) * 0.5;
            double s = (vv >= 1.0) ? 1.0 : 0.0;
            vv *= (1.0 - s);
            v[r] = vv;
            accv[r] += (float)s;
            Wb[(o << 6) + lane] = accv[r];       // exact integer in f32
        }
    }

    if (b < B) {
        #pragma unroll
        for (int r = 0; r < RPW; ++r) {
            int o = R0 + r;
            if (o < NE) out[(size_t)b * NE + o] = accv[r];
        }
    }
}

extern "C" void kernel_launch(void* const* d_in, const int* in_sizes, int n_in,
                              void* d_out, int out_size, void* d_ws, size_t ws_size,
                              hipStream_t stream) {
    const int*   actions = (const int*)  d_in[0];
    const float* spk     = (const float*)d_in[1];
    const float* W_rec   = (const float*)d_in[2];
    const float* W_inh   = (const float*)d_in[3];
    const int*   nt      = (const int*)  d_in[4];
    float* out = (float*)d_out;
    int B = in_sizes[0];

    int*  wsI = (int*)d_ws;
    char* wsB = (char*)d_ws;

    prep_kernel<<<1, 256, 0, stream>>>(W_rec, wsI, wsB);
    int nblocks = (B + NB - 1) / NB;
    snn_kernel<<<nblocks, THREADS, 0, stream>>>(actions, spk, W_inh, wsI, wsB,
                                                nt, out, B);
}